// Round 15
// baseline (168.732 us; speedup 1.0000x reference)
//
#include <hip/hip_runtime.h>
#include <hip/hip_bf16.h>
#include <math.h>

// ---------------------------------------------------------------------------
// GATv2 x2 layers, N=50000, d=128, E=800000 (+N self loops).
// Round 15: agg software-pipelined gathers.
//  - r12 evidence: halving math stream bought only 2us -> agg latency-bound
//    on the per-iteration dependent chain (gather -> logit -> 4-step shfl
//    butterfly (~120cy DS latency) -> exp -> fma), dynamic trip count blocks
//    compiler pipelining. Fix: issue iter i+1's two gathers BEFORE computing
//    iter i. +8 VGPR (one uint4 pair), below the 64-reg occupancy cliff.
//  - everything else identical to round 14 (best: 165.2us).
// ---------------------------------------------------------------------------

#define LRELU_ATT 0.2f
#define LRELU_ACT 0.01f

typedef __attribute__((ext_vector_type(8))) short bf16x8;
typedef __attribute__((ext_vector_type(4))) float f32x4;
typedef __attribute__((ext_vector_type(2))) float f32x2;

#define SORT_BLOCKS 256
#define BUCKET_CAP  8192   // LDS edge capacity per bucket (mean ~4340)

// ---------------- helpers ----------------

__device__ __forceinline__ unsigned short f2bf(float f) {
    unsigned u = __float_as_uint(f);
    unsigned r = (u + 0x7fffu + ((u >> 16) & 1u)) >> 16;   // RNE
    return (unsigned short)r;
}

__device__ __forceinline__ bf16x8 pack8(float4 a, float4 b) {
    union { bf16x8 v; unsigned short u[8]; } t;
    t.u[0] = f2bf(a.x); t.u[1] = f2bf(a.y); t.u[2] = f2bf(a.z); t.u[3] = f2bf(a.w);
    t.u[4] = f2bf(b.x); t.u[5] = f2bf(b.y); t.u[6] = f2bf(b.z); t.u[7] = f2bf(b.w);
    return t.v;
}

__device__ __forceinline__ bf16x8 ldbf8(const unsigned short* p) {
    union { uint4 q; bf16x8 v; } t;
    t.q = *(const uint4*)p;
    return t.v;
}

// unpack 8 bf16 into 4 packed f32 pairs
__device__ __forceinline__ void unpack8p(uint4 q, f32x2* v) {
    f32x2 a;
    a.x = __uint_as_float(q.x << 16); a.y = __uint_as_float(q.x & 0xffff0000u); v[0] = a;
    a.x = __uint_as_float(q.y << 16); a.y = __uint_as_float(q.y & 0xffff0000u); v[1] = a;
    a.x = __uint_as_float(q.z << 16); a.y = __uint_as_float(q.z & 0xffff0000u); v[2] = a;
    a.x = __uint_as_float(q.w << 16); a.y = __uint_as_float(q.w & 0xffff0000u); v[3] = a;
}

// logit over 8 channels, packed: sum max(m,0.2m)*att  (== leaky_relu dot)
__device__ __forceinline__ float logit8p(const f32x2* v, const f32x2* xr2,
                                         const f32x2* at2) {
    f32x2 p; p.x = 0.f; p.y = 0.f;
    #pragma unroll
    for (int j = 0; j < 4; ++j) {
        f32x2 m = v[j] + xr2[j];
        f32x2 mm = __builtin_elementwise_max(m, m * LRELU_ATT);
        p = mm * at2[j] + p;
    }
    return p.x + p.y;
}

// ---------------- counting-sort CSR build ----------------

// pass 1 (+fused wconv): blocks [0,SORT_BLOCKS): per-block LDS bucket hist
// (transposed store). blocks [SORT_BLOCKS, SORT_BLOCKS+256): W swizzle.
__global__ __launch_bounds__(256) void histA_wconv_kernel(
    const int* __restrict__ ei, int E, int Etot, int chunk, int nbuck,
    int* __restrict__ histmat,
    const float* __restrict__ W0, const float* __restrict__ W1,
    const float* __restrict__ W2, const float* __restrict__ W3,
    unsigned short* __restrict__ Wb) {
    __shared__ int h[256];
    const int tid = threadIdx.x;
    if (blockIdx.x < SORT_BLOCKS) {
        h[tid] = 0;
        __syncthreads();
        const int b0 = blockIdx.x * chunk;
        const int b1 = min(b0 + chunk, Etot);
        for (int e = b0 + tid; e < b1; e += 256) {
            int d = (e < E) ? ei[E + e] : (e - E);
            atomicAdd(&h[d >> 8], 1);
        }
        __syncthreads();
        if (tid < nbuck) histmat[tid * SORT_BLOCKS + blockIdx.x] = h[tid];
    } else {
        // W pre-swizzle into MFMA B-fragment order.
        int g = (blockIdx.x - SORT_BLOCKS) * 256 + tid;   // 0 .. 4*16384-1
        int m = g >> 14;
        int f = g & 16383;
        int j = f & 7, l = (f >> 3) & 63, ct = (f >> 9) & 7, ks = f >> 12;
        int row = ks * 32 + ((l >> 4) << 3) + j;
        int col = ct * 16 + (l & 15);
        const float* W = m == 0 ? W0 : m == 1 ? W1 : m == 2 ? W2 : W3;
        Wb[g] = f2bf(W[row * 128 + col]);
    }
}

// pass 2a: per-bucket row reduce -> btot[b]   (one block per bucket)
__global__ __launch_bounds__(256) void scanB1_kernel(
    const int* __restrict__ histmat, int* __restrict__ btot) {
    __shared__ int s[256];
    const int b = blockIdx.x, tid = threadIdx.x;
    s[tid] = histmat[b * SORT_BLOCKS + tid];
    __syncthreads();
    #pragma unroll
    for (int d = 128; d > 0; d >>= 1) {
        if (tid < d) s[tid] += s[tid + d];
        __syncthreads();
    }
    if (tid == 0) btot[b] = s[0];
}

// pass 2b: per-bucket: replicate global scan of btot -> bbase[b]; then row
// exclusive scan + base, in-place histmat.
__global__ __launch_bounds__(256) void scanB3_kernel(
    int* __restrict__ histmat, const int* __restrict__ btot, int nbuck,
    int* __restrict__ bbase) {
    __shared__ int s[256];
    const int b = blockIdx.x, tid = threadIdx.x;

    int v = (tid < nbuck) ? btot[tid] : 0;
    s[tid] = v;
    __syncthreads();
    int sum = v;
    #pragma unroll
    for (int d = 1; d < 256; d <<= 1) {
        int t = (tid >= d) ? s[tid - d] : 0;
        __syncthreads();
        sum += t;
        s[tid] = sum;
        __syncthreads();
    }
    const int base = (b > 0) ? s[b - 1] : 0;       // exclusive bucket base
    if (tid == 0) {
        bbase[b] = base;
        if (b == nbuck - 1) bbase[nbuck] = s[nbuck - 1];
    }
    __syncthreads();

    const int rv = histmat[b * SORT_BLOCKS + tid];
    s[tid] = rv;
    __syncthreads();
    int rsum = rv;
    #pragma unroll
    for (int d = 1; d < 256; d <<= 1) {
        int t = (tid >= d) ? s[tid - d] : 0;
        __syncthreads();
        rsum += t;
        s[tid] = rsum;
        __syncthreads();
    }
    histmat[b * SORT_BLOCKS + tid] = base + rsum - rv;
}

// ---------------- MFMA dual GEMM body (256 thr = 4 waves, 128 rows) -------

template<bool INF32>
__device__ __forceinline__ void gemm_body(
    int gblk, const void* __restrict__ Xin,
    const unsigned short* __restrict__ Wb,
    const float* __restrict__ bl, const float* __restrict__ br,
    unsigned short* __restrict__ xlb, unsigned short* __restrict__ xrb, int n) {
    const int tid  = threadIdx.x;
    const int wave = tid >> 6, lane = tid & 63;
    const int rowbase = gblk * 128 + wave * 32;
    const int lrow = lane & 15;
    const int kgrp = lane >> 4;

    bf16x8 af[2][4];
    #pragma unroll
    for (int rt = 0; rt < 2; ++rt) {
        const int row = rowbase + rt * 16 + lrow;
        const bool ok = row < n;
        #pragma unroll
        for (int ks = 0; ks < 4; ++ks) {
            const int k0 = ks * 32 + kgrp * 8;
            if (INF32) {
                const float* X = (const float*)Xin;
                float4 a = make_float4(0.f, 0.f, 0.f, 0.f), b = a;
                if (ok) {
                    a = *(const float4*)(X + (size_t)row * 128 + k0);
                    b = *(const float4*)(X + (size_t)row * 128 + k0 + 4);
                }
                af[rt][ks] = pack8(a, b);
            } else {
                const unsigned short* X = (const unsigned short*)Xin;
                union { uint4 q; bf16x8 v; } t;
                t.q = make_uint4(0u, 0u, 0u, 0u);
                if (ok) t.q = *(const uint4*)(X + (size_t)row * 128 + k0);
                af[rt][ks] = t.v;
            }
        }
    }

    #pragma unroll
    for (int m = 0; m < 2; ++m) {
        const unsigned short* wb = Wb + m * 16384;
        f32x4 acc[2][8];
        #pragma unroll
        for (int rt = 0; rt < 2; ++rt)
            #pragma unroll
            for (int ct = 0; ct < 8; ++ct)
                acc[rt][ct] = (f32x4){0.f, 0.f, 0.f, 0.f};

        #pragma unroll
        for (int ct = 0; ct < 8; ++ct) {
            #pragma unroll
            for (int ks = 0; ks < 4; ++ks) {
                bf16x8 bf = ldbf8(wb + ((ks * 8 + ct) * 64 + lane) * 8);
                acc[0][ct] = __builtin_amdgcn_mfma_f32_16x16x32_bf16(af[0][ks], bf, acc[0][ct], 0, 0, 0);
                acc[1][ct] = __builtin_amdgcn_mfma_f32_16x16x32_bf16(af[1][ks], bf, acc[1][ct], 0, 0, 0);
            }
        }

        const float* bias = m ? br : bl;
        unsigned short* dst = m ? xrb : xlb;
        #pragma unroll
        for (int rt = 0; rt < 2; ++rt) {
            #pragma unroll
            for (int ct = 0; ct < 8; ++ct) {
                const int col = ct * 16 + lrow;
                const float bv = bias[col];
                #pragma unroll
                for (int i = 0; i < 4; ++i) {
                    const int row = rowbase + rt * 16 + kgrp * 4 + i;
                    if (row < n)
                        dst[(size_t)row * 128 + col] = f2bf(acc[rt][ct][i] + bv);
                }
            }
        }
    }
}

template<bool INF32>
__global__ __launch_bounds__(256) void gemm_mfma_kernel(
    const void* __restrict__ Xin, const unsigned short* __restrict__ Wb,
    const float* __restrict__ bl, const float* __restrict__ br,
    unsigned short* __restrict__ xlb, unsigned short* __restrict__ xrb, int n) {
    gemm_body<INF32>(blockIdx.x, Xin, Wb, bl, br, xlb, xrb, n);
}

// pass 3 (+fused layer-0 gemm): blocks [0,SORT_BLOCKS): scatter packed
// (dstlocal<<16)|src into bucket slices. blocks [SORT_BLOCKS, ..): gemm0.
__global__ __launch_bounds__(256) void scatter_gemm_kernel(
    const int* __restrict__ ei, int E, int Etot, int chunk, int nbuck,
    const int* __restrict__ histmat, unsigned* __restrict__ ebuf,
    const float* __restrict__ X, const unsigned short* __restrict__ Wb,
    const float* __restrict__ bl, const float* __restrict__ br,
    unsigned short* __restrict__ xlb, unsigned short* __restrict__ xrb, int n) {
    if (blockIdx.x < SORT_BLOCKS) {
        __shared__ int cur[256];
        const int tid = threadIdx.x;
        if (tid < nbuck) cur[tid] = histmat[tid * SORT_BLOCKS + blockIdx.x];
        __syncthreads();
        const int b0 = blockIdx.x * chunk;
        const int b1 = min(b0 + chunk, Etot);
        for (int e = b0 + tid; e < b1; e += 256) {
            int s, d;
            if (e < E) { s = ei[e]; d = ei[E + e]; }
            else       { s = d = e - E; }
            int pos = atomicAdd(&cur[d >> 8], 1);
            ebuf[pos] = ((unsigned)(d & 255) << 16) | (unsigned)s;
        }
    } else {
        gemm_body<true>(blockIdx.x - SORT_BLOCKS, (const void*)X, Wb, bl, br,
                        xlb, xrb, n);
    }
}

// pass 4: one block per bucket. Edges -> LDS, per-node count + scan ->
// offs + colsrc placement (block-owned region).
__global__ __launch_bounds__(512) void bucket_csr_kernel(
    const unsigned* __restrict__ ebuf, const int* __restrict__ bbase, int n,
    int nbuck, int* __restrict__ offs, int* __restrict__ colsrc) {
    __shared__ int cnt[256];
    __shared__ int cur[256];
    __shared__ unsigned eb[BUCKET_CAP];
    const int b = blockIdx.x, tid = threadIdx.x;
    const int lo = bbase[b], hi = bbase[b + 1];
    const int m = hi - lo;
    const int node0 = b << 8;
    const bool inl = (m <= BUCKET_CAP);

    if (tid < 256) cnt[tid] = 0;
    __syncthreads();

    if (inl) {
        for (int i = tid; i < m; i += 512) {
            unsigned q = ebuf[lo + i];
            eb[i] = q;
            atomicAdd(&cnt[q >> 16], 1);
        }
    } else {
        for (int i = tid; i < m; i += 512)
            atomicAdd(&cnt[ebuf[lo + i] >> 16], 1);
    }
    __syncthreads();

    // scan 256 node counts (threads 0..255) -> offs + cursors
    const int deg = (tid < 256) ? cnt[tid] : 0;
    if (tid < 256) cur[tid] = deg;
    __syncthreads();
    int sum = deg;
    #pragma unroll
    for (int d = 1; d < 256; d <<= 1) {
        int t = 0;
        if (tid < 256 && tid >= d) t = cur[tid - d];
        __syncthreads();
        if (tid < 256) { sum += t; cur[tid] = sum; }
        __syncthreads();
    }
    if (tid < 256) {
        int off = lo + sum - deg;            // global exclusive offset
        if (node0 + tid < n) offs[node0 + tid] = off;
        cur[tid] = off;                      // cursor for colsrc placement
    }
    if (b == nbuck - 1 && tid == 0) offs[n] = hi;
    __syncthreads();

    // place colsrc
    if (inl) {
        for (int i = tid; i < m; i += 512) {
            unsigned q = eb[i];
            int pos = atomicAdd(&cur[q >> 16], 1);
            colsrc[pos] = (int)(q & 0xffffu);
        }
    } else {
        for (int i = tid; i < m; i += 512) {
            unsigned q = ebuf[lo + i];
            int pos = atomicAdd(&cur[q >> 16], 1);
            colsrc[pos] = (int)(q & 0xffffu);
        }
    }
}

// ---------------- fused attention + aggregation (pipelined gathers) -------
// 4 dst nodes per wave: 16-lane subgroup per node, lane owns 8 channels
// (one uint4 = 8 bf16 per gather). Butterfly 4 steps. Edge unroll x2,
// software-pipelined: iter i+1's gathers issue before iter i's compute.

template<bool OUTBF>
__global__ __launch_bounds__(256) void gat_agg_kernel(
    const unsigned short* __restrict__ xlb, const unsigned short* __restrict__ xrb,
    const float* __restrict__ att, const float* __restrict__ bo,
    const int* __restrict__ offs, const int* __restrict__ col,
    float* __restrict__ outf, unsigned short* __restrict__ outb,
    int n, int apply_act) {
    const int lane = threadIdx.x & 63;
    const int sub  = lane >> 4;
    const int sl   = lane & 15;
    const int gw   = (blockIdx.x * blockDim.x + threadIdx.x) >> 6;
    const int node = gw * 4 + sub;
    const bool valid = node < n;

    const uint4* xq = (const uint4*)xlb;
    const float4* att4 = (const float4*)att;
    f32x2 xr2[4], at2[4];
    {
        uint4 qa = make_uint4(0u, 0u, 0u, 0u);
        if (valid) qa = ((const uint4*)xrb)[(size_t)node * 16 + sl];
        unpack8p(qa, xr2);
        float4 c = att4[sl * 2], d = att4[sl * 2 + 1];
        at2[0].x = c.x; at2[0].y = c.y; at2[1].x = c.z; at2[1].y = c.w;
        at2[2].x = d.x; at2[2].y = d.y; at2[3].x = d.z; at2[3].y = d.w;
    }

    f32x2 acc[4];
    #pragma unroll
    for (int j = 0; j < 4; ++j) { acc[j].x = 0.f; acc[j].y = 0.f; }
    float den = 0.f;

    int b = 0, cnt = 0;
    if (valid) { b = offs[node]; cnt = offs[node + 1] - b; }

    const int npair = cnt >> 1;
    uint4 q0, q1;
    if (npair > 0) {
        const int s0 = col[b], s1 = col[b + 1];
        q0 = xq[(size_t)s0 * 16 + sl];
        q1 = xq[(size_t)s1 * 16 + sl];
    }
    for (int i = 0; i < npair; ++i) {
        uint4 nq0, nq1;
        if (i + 1 < npair) {                 // prefetch next pair's rows
            const int s0 = col[b + 2 * i + 2], s1 = col[b + 2 * i + 3];
            nq0 = xq[(size_t)s0 * 16 + sl];
            nq1 = xq[(size_t)s1 * 16 + sl];
        }
        f32x2 v0[4], v1[4];
        unpack8p(q0, v0);
        unpack8p(q1, v1);
        float p0 = logit8p(v0, xr2, at2);
        float p1 = logit8p(v1, xr2, at2);
        p0 += __shfl_xor(p0, 1, 64);  p1 += __shfl_xor(p1, 1, 64);
        p0 += __shfl_xor(p0, 2, 64);  p1 += __shfl_xor(p1, 2, 64);
        p0 += __shfl_xor(p0, 4, 64);  p1 += __shfl_xor(p1, 4, 64);
        p0 += __shfl_xor(p0, 8, 64);  p1 += __shfl_xor(p1, 8, 64);
        const float e0 = __expf(p0), e1 = __expf(p1);
        #pragma unroll
        for (int j = 0; j < 4; ++j) {
            acc[j] = v0[j] * e0 + acc[j];
            acc[j] = v1[j] * e1 + acc[j];
        }
        den += e0 + e1;
        q0 = nq0;                            // garbage on last iter, unused
        q1 = nq1;
    }
    if (cnt & 1) {
        const int s0 = col[b + cnt - 1];
        uint4 qt = xq[(size_t)s0 * 16 + sl];
        f32x2 v0[4];
        unpack8p(qt, v0);
        float p0 = logit8p(v0, xr2, at2);
        p0 += __shfl_xor(p0, 1, 64);
        p0 += __shfl_xor(p0, 2, 64);
        p0 += __shfl_xor(p0, 4, 64);
        p0 += __shfl_xor(p0, 8, 64);
        const float e0 = __expf(p0);
        #pragma unroll
        for (int j = 0; j < 4; ++j) acc[j] = v0[j] * e0 + acc[j];
        den += e0;
    }

    if (valid) {
        const float inv = 1.f / (den + 1e-16f);
        float4 b1 = ((const float4*)bo)[sl * 2];
        float4 b2 = ((const float4*)bo)[sl * 2 + 1];
        float bov[8] = {b1.x, b1.y, b1.z, b1.w, b2.x, b2.y, b2.z, b2.w};
        float o[8];
        #pragma unroll
        for (int j = 0; j < 4; ++j) {
            o[2 * j]     = acc[j].x * inv + bov[2 * j];
            o[2 * j + 1] = acc[j].y * inv + bov[2 * j + 1];
        }
        if (apply_act) {
            #pragma unroll
            for (int j = 0; j < 8; ++j) o[j] = o[j] > 0.f ? o[j] : LRELU_ACT * o[j];
        }
        if (OUTBF) {
            ushort4 u0, u1;
            u0.x = f2bf(o[0]); u0.y = f2bf(o[1]); u0.z = f2bf(o[2]); u0.w = f2bf(o[3]);
            u1.x = f2bf(o[4]); u1.y = f2bf(o[5]); u1.z = f2bf(o[6]); u1.w = f2bf(o[7]);
            ushort4* ob = (ushort4*)(outb + (size_t)node * 128 + sl * 8);
            ob[0] = u0; ob[1] = u1;
        } else {
            float4* o4 = (float4*)(outf + (size_t)node * 128 + sl * 8);
            o4[0] = make_float4(o[0], o[1], o[2], o[3]);
            o4[1] = make_float4(o[4], o[5], o[6], o[7]);
        }
    }
}

// ---------------- host launch ----------------

static inline size_t align_up(size_t x, size_t a) { return (x + a - 1) & ~(a - 1); }

extern "C" void kernel_launch(void* const* d_in, const int* in_sizes, int n_in,
                              void* d_out, int out_size, void* d_ws, size_t ws_size,
                              hipStream_t stream) {
    const float* x   = (const float*)d_in[0];
    const int*   ei  = (const int*)d_in[1];     // int32 per harness contract
    const float* Wl0 = (const float*)d_in[2];
    const float* bl0 = (const float*)d_in[3];
    const float* Wr0 = (const float*)d_in[4];
    const float* br0 = (const float*)d_in[5];
    const float* att0= (const float*)d_in[6];
    const float* bo0 = (const float*)d_in[7];
    const float* Wl1 = (const float*)d_in[8];
    const float* bl1 = (const float*)d_in[9];
    const float* Wr1 = (const float*)d_in[10];
    const float* br1 = (const float*)d_in[11];
    const float* att1= (const float*)d_in[12];
    const float* bo1 = (const float*)d_in[13];
    float* outp = (float*)d_out;

    const int N     = in_sizes[0] / 128;
    const int E     = in_sizes[1] / 2;
    const int Etot  = E + N;
    const int NBUCK = (N + 255) >> 8;        // 196 buckets of 256 nodes
    const int CHUNK = (Etot + SORT_BLOCKS - 1) / SORT_BLOCKS;

    // workspace layout (~37 MB)
    char* p = (char*)d_ws;
    size_t off = 0;
    unsigned short* xlb = (unsigned short*)(p + off);
    off = align_up(off + (size_t)N * 128 * 2, 256);
    unsigned short* xrb = (unsigned short*)(p + off);
    off = align_up(off + (size_t)N * 128 * 2, 256);
    unsigned short* Wb = (unsigned short*)(p + off);
    off = align_up(off + (size_t)4 * 16384 * 2, 256);
    int* histmat= (int*)(p + off); off = align_up(off + (size_t)NBUCK * SORT_BLOCKS * 4, 256);
    int* btot   = (int*)(p + off); off = align_up(off + (size_t)NBUCK * 4, 256);
    int* bbase  = (int*)(p + off); off = align_up(off + (size_t)(NBUCK + 1) * 4, 256);
    int* offs   = (int*)(p + off); off = align_up(off + (size_t)(N + 1) * 4, 256);
    int* colsrc = (int*)(p + off); off = align_up(off + (size_t)Etot * 4, 256);
    unsigned* ebuf = (unsigned*)(p + off); off = align_up(off + (size_t)Etot * 4, 256);
    unsigned short* hb = (unsigned short*)d_out;   // inter-layer bf16 h
    (void)ws_size;

    const int nbGemm = (N + 127) / 128;      // 256-thr / 128-row gemm blocks

    // ---- CSR build (counting sort) + fused wconv + fused layer-0 gemm ----
    histA_wconv_kernel<<<SORT_BLOCKS + 256, 256, 0, stream>>>(
        ei, E, Etot, CHUNK, NBUCK, histmat, Wl0, Wr0, Wl1, Wr1, Wb);
    scanB1_kernel<<<NBUCK, 256, 0, stream>>>(histmat, btot);
    scanB3_kernel<<<NBUCK, 256, 0, stream>>>(histmat, btot, NBUCK, bbase);
    scatter_gemm_kernel<<<SORT_BLOCKS + nbGemm, 256, 0, stream>>>(
        ei, E, Etot, CHUNK, NBUCK, histmat, ebuf,
        x, Wb, bl0, br0, xlb, xrb, N);
    bucket_csr_kernel<<<NBUCK, 512, 0, stream>>>(ebuf, bbase, N, NBUCK, offs, colsrc);

    const int nbAgg = (N + 15) / 16;         // 16 dst nodes per 256-thr block

    // ---- layer 0 agg ----
    gat_agg_kernel<true><<<nbAgg, 256, 0, stream>>>(
        xlb, xrb, att0, bo0, offs, colsrc, nullptr, hb, N, 1);

    // ---- layer 1 ----
    gemm_mfma_kernel<false><<<nbGemm, 256, 0, stream>>>(
        (const void*)hb, Wb + 2 * 16384, bl1, br1, xlb, xrb, N);
    gat_agg_kernel<false><<<nbAgg, 256, 0, stream>>>(
        xlb, xrb, att1, bo1, offs, colsrc, outp, nullptr, N, 0);
}

// Round 16
// 162.154 us; speedup vs baseline: 1.0406x; 1.0406x over previous
//
#include <hip/hip_runtime.h>
#include <hip/hip_bf16.h>
#include <math.h>

// ---------------------------------------------------------------------------
// GATv2 x2 layers, N=50000, d=128, E=800000 (+N self loops).
// Round 16:
//  - r15 prefetch reverted (VGPR 44 -> occ 35%, +2.8us; compiler already
//    dual-issues the gathers).
//  - agg: 2 nodes/wave (2 subgroups x unroll2 per node = 4 edges/node/iter).
//    Same per-edge cost, same 8-row MLP, VGPR ~same; wave padding drops
//    E[max4 ceil(d/2)]/mean = 35% -> E[max2 ceil(d/4)]*4/17 = ~22%.
//    Final cross-subgroup combine = one shfl_xor(16) pass per node.
//  - scanB1+scanB3 merged into scanB (blocks read-only histmat -> disjoint
//    histpos rows + own bbase entry; no race). One less launch.
// ---------------------------------------------------------------------------

#define LRELU_ATT 0.2f
#define LRELU_ACT 0.01f

typedef __attribute__((ext_vector_type(8))) short bf16x8;
typedef __attribute__((ext_vector_type(4))) float f32x4;
typedef __attribute__((ext_vector_type(2))) float f32x2;

#define SORT_BLOCKS 256
#define BUCKET_CAP  8192   // LDS edge capacity per bucket (mean ~4340)

// ---------------- helpers ----------------

__device__ __forceinline__ unsigned short f2bf(float f) {
    unsigned u = __float_as_uint(f);
    unsigned r = (u + 0x7fffu + ((u >> 16) & 1u)) >> 16;   // RNE
    return (unsigned short)r;
}

__device__ __forceinline__ bf16x8 pack8(float4 a, float4 b) {
    union { bf16x8 v; unsigned short u[8]; } t;
    t.u[0] = f2bf(a.x); t.u[1] = f2bf(a.y); t.u[2] = f2bf(a.z); t.u[3] = f2bf(a.w);
    t.u[4] = f2bf(b.x); t.u[5] = f2bf(b.y); t.u[6] = f2bf(b.z); t.u[7] = f2bf(b.w);
    return t.v;
}

__device__ __forceinline__ bf16x8 ldbf8(const unsigned short* p) {
    union { uint4 q; bf16x8 v; } t;
    t.q = *(const uint4*)p;
    return t.v;
}

// unpack 8 bf16 into 4 packed f32 pairs
__device__ __forceinline__ void unpack8p(uint4 q, f32x2* v) {
    f32x2 a;
    a.x = __uint_as_float(q.x << 16); a.y = __uint_as_float(q.x & 0xffff0000u); v[0] = a;
    a.x = __uint_as_float(q.y << 16); a.y = __uint_as_float(q.y & 0xffff0000u); v[1] = a;
    a.x = __uint_as_float(q.z << 16); a.y = __uint_as_float(q.z & 0xffff0000u); v[2] = a;
    a.x = __uint_as_float(q.w << 16); a.y = __uint_as_float(q.w & 0xffff0000u); v[3] = a;
}

// logit over 8 channels, packed: sum max(m,0.2m)*att  (== leaky_relu dot)
__device__ __forceinline__ float logit8p(const f32x2* v, const f32x2* xr2,
                                         const f32x2* at2) {
    f32x2 p; p.x = 0.f; p.y = 0.f;
    #pragma unroll
    for (int j = 0; j < 4; ++j) {
        f32x2 m = v[j] + xr2[j];
        f32x2 mm = __builtin_elementwise_max(m, m * LRELU_ATT);
        p = mm * at2[j] + p;
    }
    return p.x + p.y;
}

// ---------------- counting-sort CSR build ----------------

// pass 1 (+fused wconv): blocks [0,SORT_BLOCKS): per-block LDS bucket hist
// (transposed store). blocks [SORT_BLOCKS, SORT_BLOCKS+256): W swizzle.
__global__ __launch_bounds__(256) void histA_wconv_kernel(
    const int* __restrict__ ei, int E, int Etot, int chunk, int nbuck,
    int* __restrict__ histmat,
    const float* __restrict__ W0, const float* __restrict__ W1,
    const float* __restrict__ W2, const float* __restrict__ W3,
    unsigned short* __restrict__ Wb) {
    __shared__ int h[256];
    const int tid = threadIdx.x;
    if (blockIdx.x < SORT_BLOCKS) {
        h[tid] = 0;
        __syncthreads();
        const int b0 = blockIdx.x * chunk;
        const int b1 = min(b0 + chunk, Etot);
        for (int e = b0 + tid; e < b1; e += 256) {
            int d = (e < E) ? ei[E + e] : (e - E);
            atomicAdd(&h[d >> 8], 1);
        }
        __syncthreads();
        if (tid < nbuck) histmat[tid * SORT_BLOCKS + blockIdx.x] = h[tid];
    } else {
        // W pre-swizzle into MFMA B-fragment order.
        int g = (blockIdx.x - SORT_BLOCKS) * 256 + tid;   // 0 .. 4*16384-1
        int m = g >> 14;
        int f = g & 16383;
        int j = f & 7, l = (f >> 3) & 63, ct = (f >> 9) & 7, ks = f >> 12;
        int row = ks * 32 + ((l >> 4) << 3) + j;
        int col = ct * 16 + (l & 15);
        const float* W = m == 0 ? W0 : m == 1 ? W1 : m == 2 ? W2 : W3;
        Wb[g] = f2bf(W[row * 128 + col]);
    }
}

// pass 2 (merged): each block b reads ALL of histmat (read-only), computes
// bucket totals + exclusive bucket bases, then writes the scanned row b to
// histpos and bbase[b]. Disjoint writes -> no race.
__global__ __launch_bounds__(256) void scanB_kernel(
    const int* __restrict__ histmat, int nbuck,
    int* __restrict__ histpos, int* __restrict__ bbase) {
    __shared__ int s[256];
    const int b = blockIdx.x, tid = threadIdx.x;

    // thread t sums row t (vectorized int4, pipelined)
    int total = 0;
    if (tid < nbuck) {
        const int4* p = (const int4*)(histmat + tid * SORT_BLOCKS);
        #pragma unroll 8
        for (int k = 0; k < SORT_BLOCKS / 4; ++k) {
            int4 v = p[k];
            total += v.x + v.y + v.z + v.w;
        }
    }
    s[tid] = total;
    __syncthreads();
    int sum = total;
    #pragma unroll
    for (int d = 1; d < 256; d <<= 1) {
        int t = (tid >= d) ? s[tid - d] : 0;
        __syncthreads();
        sum += t;
        s[tid] = sum;
        __syncthreads();
    }
    const int base = (b > 0) ? s[b - 1] : 0;       // exclusive bucket base
    if (tid == 0) {
        bbase[b] = base;
        if (b == nbuck - 1) bbase[nbuck] = s[nbuck - 1];
    }
    __syncthreads();

    // row b exclusive scan + base -> histpos
    const int rv = histmat[b * SORT_BLOCKS + tid];
    s[tid] = rv;
    __syncthreads();
    int rsum = rv;
    #pragma unroll
    for (int d = 1; d < 256; d <<= 1) {
        int t = (tid >= d) ? s[tid - d] : 0;
        __syncthreads();
        rsum += t;
        s[tid] = rsum;
        __syncthreads();
    }
    histpos[b * SORT_BLOCKS + tid] = base + rsum - rv;
}

// ---------------- MFMA dual GEMM body (256 thr = 4 waves, 128 rows) -------

template<bool INF32>
__device__ __forceinline__ void gemm_body(
    int gblk, const void* __restrict__ Xin,
    const unsigned short* __restrict__ Wb,
    const float* __restrict__ bl, const float* __restrict__ br,
    unsigned short* __restrict__ xlb, unsigned short* __restrict__ xrb, int n) {
    const int tid  = threadIdx.x;
    const int wave = tid >> 6, lane = tid & 63;
    const int rowbase = gblk * 128 + wave * 32;
    const int lrow = lane & 15;
    const int kgrp = lane >> 4;

    bf16x8 af[2][4];
    #pragma unroll
    for (int rt = 0; rt < 2; ++rt) {
        const int row = rowbase + rt * 16 + lrow;
        const bool ok = row < n;
        #pragma unroll
        for (int ks = 0; ks < 4; ++ks) {
            const int k0 = ks * 32 + kgrp * 8;
            if (INF32) {
                const float* X = (const float*)Xin;
                float4 a = make_float4(0.f, 0.f, 0.f, 0.f), b = a;
                if (ok) {
                    a = *(const float4*)(X + (size_t)row * 128 + k0);
                    b = *(const float4*)(X + (size_t)row * 128 + k0 + 4);
                }
                af[rt][ks] = pack8(a, b);
            } else {
                const unsigned short* X = (const unsigned short*)Xin;
                union { uint4 q; bf16x8 v; } t;
                t.q = make_uint4(0u, 0u, 0u, 0u);
                if (ok) t.q = *(const uint4*)(X + (size_t)row * 128 + k0);
                af[rt][ks] = t.v;
            }
        }
    }

    #pragma unroll
    for (int m = 0; m < 2; ++m) {
        const unsigned short* wb = Wb + m * 16384;
        f32x4 acc[2][8];
        #pragma unroll
        for (int rt = 0; rt < 2; ++rt)
            #pragma unroll
            for (int ct = 0; ct < 8; ++ct)
                acc[rt][ct] = (f32x4){0.f, 0.f, 0.f, 0.f};

        #pragma unroll
        for (int ct = 0; ct < 8; ++ct) {
            #pragma unroll
            for (int ks = 0; ks < 4; ++ks) {
                bf16x8 bf = ldbf8(wb + ((ks * 8 + ct) * 64 + lane) * 8);
                acc[0][ct] = __builtin_amdgcn_mfma_f32_16x16x32_bf16(af[0][ks], bf, acc[0][ct], 0, 0, 0);
                acc[1][ct] = __builtin_amdgcn_mfma_f32_16x16x32_bf16(af[1][ks], bf, acc[1][ct], 0, 0, 0);
            }
        }

        const float* bias = m ? br : bl;
        unsigned short* dst = m ? xrb : xlb;
        #pragma unroll
        for (int rt = 0; rt < 2; ++rt) {
            #pragma unroll
            for (int ct = 0; ct < 8; ++ct) {
                const int col = ct * 16 + lrow;
                const float bv = bias[col];
                #pragma unroll
                for (int i = 0; i < 4; ++i) {
                    const int row = rowbase + rt * 16 + kgrp * 4 + i;
                    if (row < n)
                        dst[(size_t)row * 128 + col] = f2bf(acc[rt][ct][i] + bv);
                }
            }
        }
    }
}

template<bool INF32>
__global__ __launch_bounds__(256) void gemm_mfma_kernel(
    const void* __restrict__ Xin, const unsigned short* __restrict__ Wb,
    const float* __restrict__ bl, const float* __restrict__ br,
    unsigned short* __restrict__ xlb, unsigned short* __restrict__ xrb, int n) {
    gemm_body<INF32>(blockIdx.x, Xin, Wb, bl, br, xlb, xrb, n);
}

// pass 3 (+fused layer-0 gemm): blocks [0,SORT_BLOCKS): scatter packed
// (dstlocal<<16)|src into bucket slices. blocks [SORT_BLOCKS, ..): gemm0.
__global__ __launch_bounds__(256) void scatter_gemm_kernel(
    const int* __restrict__ ei, int E, int Etot, int chunk, int nbuck,
    const int* __restrict__ histpos, unsigned* __restrict__ ebuf,
    const float* __restrict__ X, const unsigned short* __restrict__ Wb,
    const float* __restrict__ bl, const float* __restrict__ br,
    unsigned short* __restrict__ xlb, unsigned short* __restrict__ xrb, int n) {
    if (blockIdx.x < SORT_BLOCKS) {
        __shared__ int cur[256];
        const int tid = threadIdx.x;
        if (tid < nbuck) cur[tid] = histpos[tid * SORT_BLOCKS + blockIdx.x];
        __syncthreads();
        const int b0 = blockIdx.x * chunk;
        const int b1 = min(b0 + chunk, Etot);
        for (int e = b0 + tid; e < b1; e += 256) {
            int s, d;
            if (e < E) { s = ei[e]; d = ei[E + e]; }
            else       { s = d = e - E; }
            int pos = atomicAdd(&cur[d >> 8], 1);
            ebuf[pos] = ((unsigned)(d & 255) << 16) | (unsigned)s;
        }
    } else {
        gemm_body<true>(blockIdx.x - SORT_BLOCKS, (const void*)X, Wb, bl, br,
                        xlb, xrb, n);
    }
}

// pass 4: one block per bucket. Edges -> LDS, per-node count + scan ->
// offs + colsrc placement (block-owned region).
__global__ __launch_bounds__(512) void bucket_csr_kernel(
    const unsigned* __restrict__ ebuf, const int* __restrict__ bbase, int n,
    int nbuck, int* __restrict__ offs, int* __restrict__ colsrc) {
    __shared__ int cnt[256];
    __shared__ int cur[256];
    __shared__ unsigned eb[BUCKET_CAP];
    const int b = blockIdx.x, tid = threadIdx.x;
    const int lo = bbase[b], hi = bbase[b + 1];
    const int m = hi - lo;
    const int node0 = b << 8;
    const bool inl = (m <= BUCKET_CAP);

    if (tid < 256) cnt[tid] = 0;
    __syncthreads();

    if (inl) {
        for (int i = tid; i < m; i += 512) {
            unsigned q = ebuf[lo + i];
            eb[i] = q;
            atomicAdd(&cnt[q >> 16], 1);
        }
    } else {
        for (int i = tid; i < m; i += 512)
            atomicAdd(&cnt[ebuf[lo + i] >> 16], 1);
    }
    __syncthreads();

    // scan 256 node counts (threads 0..255) -> offs + cursors
    const int deg = (tid < 256) ? cnt[tid] : 0;
    if (tid < 256) cur[tid] = deg;
    __syncthreads();
    int sum = deg;
    #pragma unroll
    for (int d = 1; d < 256; d <<= 1) {
        int t = 0;
        if (tid < 256 && tid >= d) t = cur[tid - d];
        __syncthreads();
        if (tid < 256) { sum += t; cur[tid] = sum; }
        __syncthreads();
    }
    if (tid < 256) {
        int off = lo + sum - deg;            // global exclusive offset
        if (node0 + tid < n) offs[node0 + tid] = off;
        cur[tid] = off;                      // cursor for colsrc placement
    }
    if (b == nbuck - 1 && tid == 0) offs[n] = hi;
    __syncthreads();

    // place colsrc
    if (inl) {
        for (int i = tid; i < m; i += 512) {
            unsigned q = eb[i];
            int pos = atomicAdd(&cur[q >> 16], 1);
            colsrc[pos] = (int)(q & 0xffffu);
        }
    } else {
        for (int i = tid; i < m; i += 512) {
            unsigned q = ebuf[lo + i];
            int pos = atomicAdd(&cur[q >> 16], 1);
            colsrc[pos] = (int)(q & 0xffffu);
        }
    }
}

// ---------------- fused attention + aggregation (2 nodes/wave) ------------
// wave = 2 nodes; per node 2 subgroups (16-lane) x unroll 2 = 4 edges/iter.
// lane: nh = lane>>5 (node half), ss = (lane>>4)&1 (edge slot), sl = lane&15
// (channel group, 8 ch via uint4 gather). Butterfly 4 steps within subgroup;
// final combine = shfl_xor(16) once. pk-f32 math.

template<bool OUTBF>
__global__ __launch_bounds__(256) void gat_agg_kernel(
    const unsigned short* __restrict__ xlb, const unsigned short* __restrict__ xrb,
    const float* __restrict__ att, const float* __restrict__ bo,
    const int* __restrict__ offs, const int* __restrict__ col,
    float* __restrict__ outf, unsigned short* __restrict__ outb,
    int n, int apply_act) {
    const int lane = threadIdx.x & 63;
    const int nh   = lane >> 5;              // node half
    const int ss   = (lane >> 4) & 1;        // edge slot within node
    const int sl   = lane & 15;              // channel group
    const int gw   = (blockIdx.x * blockDim.x + threadIdx.x) >> 6;
    const int node = gw * 2 + nh;
    const bool valid = node < n;

    const uint4* xq = (const uint4*)xlb;
    const float4* att4 = (const float4*)att;
    f32x2 xr2[4], at2[4];
    {
        uint4 qa = make_uint4(0u, 0u, 0u, 0u);
        if (valid) qa = ((const uint4*)xrb)[(size_t)node * 16 + sl];
        unpack8p(qa, xr2);
        float4 c = att4[sl * 2], d = att4[sl * 2 + 1];
        at2[0].x = c.x; at2[0].y = c.y; at2[1].x = c.z; at2[1].y = c.w;
        at2[2].x = d.x; at2[2].y = d.y; at2[3].x = d.z; at2[3].y = d.w;
    }

    f32x2 acc[4];
    #pragma unroll
    for (int j = 0; j < 4; ++j) { acc[j].x = 0.f; acc[j].y = 0.f; }
    float den = 0.f;

    int b = 0, cnt = 0;
    if (valid) { b = offs[node]; cnt = offs[node + 1] - b; }

    for (int k = 0; k < cnt; k += 4) {
        const int k0 = k + ss;               // edge index slot 0
        const int k1 = k + 2 + ss;           // edge index slot 1
        const bool e0v = k0 < cnt, e1v = k1 < cnt;
        const int s0 = col[b + (e0v ? k0 : 0)];
        const int s1 = col[b + (e1v ? k1 : 0)];
        uint4 q0 = xq[(size_t)s0 * 16 + sl];
        uint4 q1 = xq[(size_t)s1 * 16 + sl];
        f32x2 v0[4], v1[4];
        unpack8p(q0, v0);
        unpack8p(q1, v1);
        float p0 = logit8p(v0, xr2, at2);
        float p1 = logit8p(v1, xr2, at2);
        p0 += __shfl_xor(p0, 1, 64);  p1 += __shfl_xor(p1, 1, 64);
        p0 += __shfl_xor(p0, 2, 64);  p1 += __shfl_xor(p1, 2, 64);
        p0 += __shfl_xor(p0, 4, 64);  p1 += __shfl_xor(p1, 4, 64);
        p0 += __shfl_xor(p0, 8, 64);  p1 += __shfl_xor(p1, 8, 64);
        const float e0 = e0v ? __expf(p0) : 0.f;
        const float e1 = e1v ? __expf(p1) : 0.f;
        #pragma unroll
        for (int j = 0; j < 4; ++j) {
            acc[j] = v0[j] * e0 + acc[j];
            acc[j] = v1[j] * e1 + acc[j];
        }
        den += e0 + e1;
    }

    // combine the node's two subgroups (lanes ^16)
    den += __shfl_xor(den, 16, 64);
    #pragma unroll
    for (int j = 0; j < 4; ++j) {
        acc[j].x += __shfl_xor(acc[j].x, 16, 64);
        acc[j].y += __shfl_xor(acc[j].y, 16, 64);
    }

    if (valid && ss == 0) {
        const float inv = 1.f / (den + 1e-16f);
        float4 b1 = ((const float4*)bo)[sl * 2];
        float4 b2 = ((const float4*)bo)[sl * 2 + 1];
        float bov[8] = {b1.x, b1.y, b1.z, b1.w, b2.x, b2.y, b2.z, b2.w};
        float o[8];
        #pragma unroll
        for (int j = 0; j < 4; ++j) {
            o[2 * j]     = acc[j].x * inv + bov[2 * j];
            o[2 * j + 1] = acc[j].y * inv + bov[2 * j + 1];
        }
        if (apply_act) {
            #pragma unroll
            for (int j = 0; j < 8; ++j) o[j] = o[j] > 0.f ? o[j] : LRELU_ACT * o[j];
        }
        if (OUTBF) {
            ushort4 u0, u1;
            u0.x = f2bf(o[0]); u0.y = f2bf(o[1]); u0.z = f2bf(o[2]); u0.w = f2bf(o[3]);
            u1.x = f2bf(o[4]); u1.y = f2bf(o[5]); u1.z = f2bf(o[6]); u1.w = f2bf(o[7]);
            ushort4* ob = (ushort4*)(outb + (size_t)node * 128 + sl * 8);
            ob[0] = u0; ob[1] = u1;
        } else {
            float4* o4 = (float4*)(outf + (size_t)node * 128 + sl * 8);
            o4[0] = make_float4(o[0], o[1], o[2], o[3]);
            o4[1] = make_float4(o[4], o[5], o[6], o[7]);
        }
    }
}

// ---------------- host launch ----------------

static inline size_t align_up(size_t x, size_t a) { return (x + a - 1) & ~(a - 1); }

extern "C" void kernel_launch(void* const* d_in, const int* in_sizes, int n_in,
                              void* d_out, int out_size, void* d_ws, size_t ws_size,
                              hipStream_t stream) {
    const float* x   = (const float*)d_in[0];
    const int*   ei  = (const int*)d_in[1];     // int32 per harness contract
    const float* Wl0 = (const float*)d_in[2];
    const float* bl0 = (const float*)d_in[3];
    const float* Wr0 = (const float*)d_in[4];
    const float* br0 = (const float*)d_in[5];
    const float* att0= (const float*)d_in[6];
    const float* bo0 = (const float*)d_in[7];
    const float* Wl1 = (const float*)d_in[8];
    const float* bl1 = (const float*)d_in[9];
    const float* Wr1 = (const float*)d_in[10];
    const float* br1 = (const float*)d_in[11];
    const float* att1= (const float*)d_in[12];
    const float* bo1 = (const float*)d_in[13];
    float* outp = (float*)d_out;

    const int N     = in_sizes[0] / 128;
    const int E     = in_sizes[1] / 2;
    const int Etot  = E + N;
    const int NBUCK = (N + 255) >> 8;        // 196 buckets of 256 nodes
    const int CHUNK = (Etot + SORT_BLOCKS - 1) / SORT_BLOCKS;

    // workspace layout (~37 MB)
    char* p = (char*)d_ws;
    size_t off = 0;
    unsigned short* xlb = (unsigned short*)(p + off);
    off = align_up(off + (size_t)N * 128 * 2, 256);
    unsigned short* xrb = (unsigned short*)(p + off);
    off = align_up(off + (size_t)N * 128 * 2, 256);
    unsigned short* Wb = (unsigned short*)(p + off);
    off = align_up(off + (size_t)4 * 16384 * 2, 256);
    int* histmat= (int*)(p + off); off = align_up(off + (size_t)NBUCK * SORT_BLOCKS * 4, 256);
    int* histpos= (int*)(p + off); off = align_up(off + (size_t)NBUCK * SORT_BLOCKS * 4, 256);
    int* bbase  = (int*)(p + off); off = align_up(off + (size_t)(NBUCK + 1) * 4, 256);
    int* offs   = (int*)(p + off); off = align_up(off + (size_t)(N + 1) * 4, 256);
    int* colsrc = (int*)(p + off); off = align_up(off + (size_t)Etot * 4, 256);
    unsigned* ebuf = (unsigned*)(p + off); off = align_up(off + (size_t)Etot * 4, 256);
    unsigned short* hb = (unsigned short*)d_out;   // inter-layer bf16 h
    (void)ws_size;

    const int nbGemm = (N + 127) / 128;      // 256-thr / 128-row gemm blocks

    // ---- CSR build (counting sort) + fused wconv + fused layer-0 gemm ----
    histA_wconv_kernel<<<SORT_BLOCKS + 256, 256, 0, stream>>>(
        ei, E, Etot, CHUNK, NBUCK, histmat, Wl0, Wr0, Wl1, Wr1, Wb);
    scanB_kernel<<<NBUCK, 256, 0, stream>>>(histmat, NBUCK, histpos, bbase);
    scatter_gemm_kernel<<<SORT_BLOCKS + nbGemm, 256, 0, stream>>>(
        ei, E, Etot, CHUNK, NBUCK, histpos, ebuf,
        x, Wb, bl0, br0, xlb, xrb, N);
    bucket_csr_kernel<<<NBUCK, 512, 0, stream>>>(ebuf, bbase, N, NBUCK, offs, colsrc);

    const int nbAgg = (N + 7) / 8;           // 8 dst nodes per 256-thr block

    // ---- layer 0 agg ----
    gat_agg_kernel<true><<<nbAgg, 256, 0, stream>>>(
        xlb, xrb, att0, bo0, offs, colsrc, nullptr, hb, N, 1);

    // ---- layer 1 ----
    gemm_mfma_kernel<false><<<nbGemm, 256, 0, stream>>>(
        (const void*)hb, Wb + 2 * 16384, bl1, br1, xlb, xrb, N);
    gat_agg_kernel<false><<<nbAgg, 256, 0, stream>>>(
        xlb, xrb, att1, bo1, offs, colsrc, outp, nullptr, N, 0);
}

// Round 18
// 162.056 us; speedup vs baseline: 1.0412x; 1.0006x over previous
//
#include <hip/hip_runtime.h>
#include <hip/hip_bf16.h>
#include <math.h>

// ---------------------------------------------------------------------------
// GATv2 x2 layers, N=50000, d=128, E=800000 (+N self loops).
// Round 18: revert to round-16 (best measured, 162.2us). Round-17 coop fusion
// failed (silent hipLaunchCooperativeKernel rejection -> zeros) and is
// structurally unprofitable: coop caps co-residency at 256 blocks, killing
// the oversubscribed scatter||gemm0 overlap that makes gemm0 free.
// Configuration:
//  - agg: 2 nodes/wave, 2 subgroups x unroll2 per node, 8ch/lane uint4
//    gathers, pk-f32 math (44.6us, VALUBusy 57%, occ 45%).
//  - CSR: counting sort (histA+wconv fused; scanB merged; scatter+gemm0
//    fused; bucket_csr). bf16 xl/xr/h. MFMA gemm.
// ---------------------------------------------------------------------------

#define LRELU_ATT 0.2f
#define LRELU_ACT 0.01f

typedef __attribute__((ext_vector_type(8))) short bf16x8;
typedef __attribute__((ext_vector_type(4))) float f32x4;
typedef __attribute__((ext_vector_type(2))) float f32x2;

#define SORT_BLOCKS 256
#define BUCKET_CAP  8192   // LDS edge capacity per bucket (mean ~4340)

// ---------------- helpers ----------------

__device__ __forceinline__ unsigned short f2bf(float f) {
    unsigned u = __float_as_uint(f);
    unsigned r = (u + 0x7fffu + ((u >> 16) & 1u)) >> 16;   // RNE
    return (unsigned short)r;
}

__device__ __forceinline__ bf16x8 pack8(float4 a, float4 b) {
    union { bf16x8 v; unsigned short u[8]; } t;
    t.u[0] = f2bf(a.x); t.u[1] = f2bf(a.y); t.u[2] = f2bf(a.z); t.u[3] = f2bf(a.w);
    t.u[4] = f2bf(b.x); t.u[5] = f2bf(b.y); t.u[6] = f2bf(b.z); t.u[7] = f2bf(b.w);
    return t.v;
}

__device__ __forceinline__ bf16x8 ldbf8(const unsigned short* p) {
    union { uint4 q; bf16x8 v; } t;
    t.q = *(const uint4*)p;
    return t.v;
}

// unpack 8 bf16 into 4 packed f32 pairs
__device__ __forceinline__ void unpack8p(uint4 q, f32x2* v) {
    f32x2 a;
    a.x = __uint_as_float(q.x << 16); a.y = __uint_as_float(q.x & 0xffff0000u); v[0] = a;
    a.x = __uint_as_float(q.y << 16); a.y = __uint_as_float(q.y & 0xffff0000u); v[1] = a;
    a.x = __uint_as_float(q.z << 16); a.y = __uint_as_float(q.z & 0xffff0000u); v[2] = a;
    a.x = __uint_as_float(q.w << 16); a.y = __uint_as_float(q.w & 0xffff0000u); v[3] = a;
}

// logit over 8 channels, packed: sum max(m,0.2m)*att  (== leaky_relu dot)
__device__ __forceinline__ float logit8p(const f32x2* v, const f32x2* xr2,
                                         const f32x2* at2) {
    f32x2 p; p.x = 0.f; p.y = 0.f;
    #pragma unroll
    for (int j = 0; j < 4; ++j) {
        f32x2 m = v[j] + xr2[j];
        f32x2 mm = __builtin_elementwise_max(m, m * LRELU_ATT);
        p = mm * at2[j] + p;
    }
    return p.x + p.y;
}

// ---------------- counting-sort CSR build ----------------

// pass 1 (+fused wconv): blocks [0,SORT_BLOCKS): per-block LDS bucket hist
// (transposed store). blocks [SORT_BLOCKS, SORT_BLOCKS+256): W swizzle.
__global__ __launch_bounds__(256) void histA_wconv_kernel(
    const int* __restrict__ ei, int E, int Etot, int chunk, int nbuck,
    int* __restrict__ histmat,
    const float* __restrict__ W0, const float* __restrict__ W1,
    const float* __restrict__ W2, const float* __restrict__ W3,
    unsigned short* __restrict__ Wb) {
    __shared__ int h[256];
    const int tid = threadIdx.x;
    if (blockIdx.x < SORT_BLOCKS) {
        h[tid] = 0;
        __syncthreads();
        const int b0 = blockIdx.x * chunk;
        const int b1 = min(b0 + chunk, Etot);
        for (int e = b0 + tid; e < b1; e += 256) {
            int d = (e < E) ? ei[E + e] : (e - E);
            atomicAdd(&h[d >> 8], 1);
        }
        __syncthreads();
        if (tid < nbuck) histmat[tid * SORT_BLOCKS + blockIdx.x] = h[tid];
    } else {
        // W pre-swizzle into MFMA B-fragment order.
        int g = (blockIdx.x - SORT_BLOCKS) * 256 + tid;   // 0 .. 4*16384-1
        int m = g >> 14;
        int f = g & 16383;
        int j = f & 7, l = (f >> 3) & 63, ct = (f >> 9) & 7, ks = f >> 12;
        int row = ks * 32 + ((l >> 4) << 3) + j;
        int col = ct * 16 + (l & 15);
        const float* W = m == 0 ? W0 : m == 1 ? W1 : m == 2 ? W2 : W3;
        Wb[g] = f2bf(W[row * 128 + col]);
    }
}

// pass 2 (merged): each block b reads ALL of histmat (read-only), computes
// bucket totals + exclusive bucket bases, then writes the scanned row b to
// histpos and bbase[b]. Disjoint writes -> no race.
__global__ __launch_bounds__(256) void scanB_kernel(
    const int* __restrict__ histmat, int nbuck,
    int* __restrict__ histpos, int* __restrict__ bbase) {
    __shared__ int s[256];
    const int b = blockIdx.x, tid = threadIdx.x;

    // thread t sums row t (vectorized int4, pipelined)
    int total = 0;
    if (tid < nbuck) {
        const int4* p = (const int4*)(histmat + tid * SORT_BLOCKS);
        #pragma unroll 8
        for (int k = 0; k < SORT_BLOCKS / 4; ++k) {
            int4 v = p[k];
            total += v.x + v.y + v.z + v.w;
        }
    }
    s[tid] = total;
    __syncthreads();
    int sum = total;
    #pragma unroll
    for (int d = 1; d < 256; d <<= 1) {
        int t = (tid >= d) ? s[tid - d] : 0;
        __syncthreads();
        sum += t;
        s[tid] = sum;
        __syncthreads();
    }
    const int base = (b > 0) ? s[b - 1] : 0;       // exclusive bucket base
    if (tid == 0) {
        bbase[b] = base;
        if (b == nbuck - 1) bbase[nbuck] = s[nbuck - 1];
    }
    __syncthreads();

    // row b exclusive scan + base -> histpos
    const int rv = histmat[b * SORT_BLOCKS + tid];
    s[tid] = rv;
    __syncthreads();
    int rsum = rv;
    #pragma unroll
    for (int d = 1; d < 256; d <<= 1) {
        int t = (tid >= d) ? s[tid - d] : 0;
        __syncthreads();
        rsum += t;
        s[tid] = rsum;
        __syncthreads();
    }
    histpos[b * SORT_BLOCKS + tid] = base + rsum - rv;
}

// ---------------- MFMA dual GEMM body (256 thr = 4 waves, 128 rows) -------

template<bool INF32>
__device__ __forceinline__ void gemm_body(
    int gblk, const void* __restrict__ Xin,
    const unsigned short* __restrict__ Wb,
    const float* __restrict__ bl, const float* __restrict__ br,
    unsigned short* __restrict__ xlb, unsigned short* __restrict__ xrb, int n) {
    const int tid  = threadIdx.x;
    const int wave = tid >> 6, lane = tid & 63;
    const int rowbase = gblk * 128 + wave * 32;
    const int lrow = lane & 15;
    const int kgrp = lane >> 4;

    bf16x8 af[2][4];
    #pragma unroll
    for (int rt = 0; rt < 2; ++rt) {
        const int row = rowbase + rt * 16 + lrow;
        const bool ok = row < n;
        #pragma unroll
        for (int ks = 0; ks < 4; ++ks) {
            const int k0 = ks * 32 + kgrp * 8;
            if (INF32) {
                const float* X = (const float*)Xin;
                float4 a = make_float4(0.f, 0.f, 0.f, 0.f), b = a;
                if (ok) {
                    a = *(const float4*)(X + (size_t)row * 128 + k0);
                    b = *(const float4*)(X + (size_t)row * 128 + k0 + 4);
                }
                af[rt][ks] = pack8(a, b);
            } else {
                const unsigned short* X = (const unsigned short*)Xin;
                union { uint4 q; bf16x8 v; } t;
                t.q = make_uint4(0u, 0u, 0u, 0u);
                if (ok) t.q = *(const uint4*)(X + (size_t)row * 128 + k0);
                af[rt][ks] = t.v;
            }
        }
    }

    #pragma unroll
    for (int m = 0; m < 2; ++m) {
        const unsigned short* wb = Wb + m * 16384;
        f32x4 acc[2][8];
        #pragma unroll
        for (int rt = 0; rt < 2; ++rt)
            #pragma unroll
            for (int ct = 0; ct < 8; ++ct)
                acc[rt][ct] = (f32x4){0.f, 0.f, 0.f, 0.f};

        #pragma unroll
        for (int ct = 0; ct < 8; ++ct) {
            #pragma unroll
            for (int ks = 0; ks < 4; ++ks) {
                bf16x8 bf = ldbf8(wb + ((ks * 8 + ct) * 64 + lane) * 8);
                acc[0][ct] = __builtin_amdgcn_mfma_f32_16x16x32_bf16(af[0][ks], bf, acc[0][ct], 0, 0, 0);
                acc[1][ct] = __builtin_amdgcn_mfma_f32_16x16x32_bf16(af[1][ks], bf, acc[1][ct], 0, 0, 0);
            }
        }

        const float* bias = m ? br : bl;
        unsigned short* dst = m ? xrb : xlb;
        #pragma unroll
        for (int rt = 0; rt < 2; ++rt) {
            #pragma unroll
            for (int ct = 0; ct < 8; ++ct) {
                const int col = ct * 16 + lrow;
                const float bv = bias[col];
                #pragma unroll
                for (int i = 0; i < 4; ++i) {
                    const int row = rowbase + rt * 16 + kgrp * 4 + i;
                    if (row < n)
                        dst[(size_t)row * 128 + col] = f2bf(acc[rt][ct][i] + bv);
                }
            }
        }
    }
}

template<bool INF32>
__global__ __launch_bounds__(256) void gemm_mfma_kernel(
    const void* __restrict__ Xin, const unsigned short* __restrict__ Wb,
    const float* __restrict__ bl, const float* __restrict__ br,
    unsigned short* __restrict__ xlb, unsigned short* __restrict__ xrb, int n) {
    gemm_body<INF32>(blockIdx.x, Xin, Wb, bl, br, xlb, xrb, n);
}

// pass 3 (+fused layer-0 gemm): blocks [0,SORT_BLOCKS): scatter packed
// (dstlocal<<16)|src into bucket slices. blocks [SORT_BLOCKS, ..): gemm0.
__global__ __launch_bounds__(256) void scatter_gemm_kernel(
    const int* __restrict__ ei, int E, int Etot, int chunk, int nbuck,
    const int* __restrict__ histpos, unsigned* __restrict__ ebuf,
    const float* __restrict__ X, const unsigned short* __restrict__ Wb,
    const float* __restrict__ bl, const float* __restrict__ br,
    unsigned short* __restrict__ xlb, unsigned short* __restrict__ xrb, int n) {
    if (blockIdx.x < SORT_BLOCKS) {
        __shared__ int cur[256];
        const int tid = threadIdx.x;
        if (tid < nbuck) cur[tid] = histpos[tid * SORT_BLOCKS + blockIdx.x];
        __syncthreads();
        const int b0 = blockIdx.x * chunk;
        const int b1 = min(b0 + chunk, Etot);
        for (int e = b0 + tid; e < b1; e += 256) {
            int s, d;
            if (e < E) { s = ei[e]; d = ei[E + e]; }
            else       { s = d = e - E; }
            int pos = atomicAdd(&cur[d >> 8], 1);
            ebuf[pos] = ((unsigned)(d & 255) << 16) | (unsigned)s;
        }
    } else {
        gemm_body<true>(blockIdx.x - SORT_BLOCKS, (const void*)X, Wb, bl, br,
                        xlb, xrb, n);
    }
}

// pass 4: one block per bucket. Edges -> LDS, per-node count + scan ->
// offs + colsrc placement (block-owned region).
__global__ __launch_bounds__(512) void bucket_csr_kernel(
    const unsigned* __restrict__ ebuf, const int* __restrict__ bbase, int n,
    int nbuck, int* __restrict__ offs, int* __restrict__ colsrc) {
    __shared__ int cnt[256];
    __shared__ int cur[256];
    __shared__ unsigned eb[BUCKET_CAP];
    const int b = blockIdx.x, tid = threadIdx.x;
    const int lo = bbase[b], hi = bbase[b + 1];
    const int m = hi - lo;
    const int node0 = b << 8;
    const bool inl = (m <= BUCKET_CAP);

    if (tid < 256) cnt[tid] = 0;
    __syncthreads();

    if (inl) {
        for (int i = tid; i < m; i += 512) {
            unsigned q = ebuf[lo + i];
            eb[i] = q;
            atomicAdd(&cnt[q >> 16], 1);
        }
    } else {
        for (int i = tid; i < m; i += 512)
            atomicAdd(&cnt[ebuf[lo + i] >> 16], 1);
    }
    __syncthreads();

    // scan 256 node counts (threads 0..255) -> offs + cursors
    const int deg = (tid < 256) ? cnt[tid] : 0;
    if (tid < 256) cur[tid] = deg;
    __syncthreads();
    int sum = deg;
    #pragma unroll
    for (int d = 1; d < 256; d <<= 1) {
        int t = 0;
        if (tid < 256 && tid >= d) t = cur[tid - d];
        __syncthreads();
        if (tid < 256) { sum += t; cur[tid] = sum; }
        __syncthreads();
    }
    if (tid < 256) {
        int off = lo + sum - deg;            // global exclusive offset
        if (node0 + tid < n) offs[node0 + tid] = off;
        cur[tid] = off;                      // cursor for colsrc placement
    }
    if (b == nbuck - 1 && tid == 0) offs[n] = hi;
    __syncthreads();

    // place colsrc
    if (inl) {
        for (int i = tid; i < m; i += 512) {
            unsigned q = eb[i];
            int pos = atomicAdd(&cur[q >> 16], 1);
            colsrc[pos] = (int)(q & 0xffffu);
        }
    } else {
        for (int i = tid; i < m; i += 512) {
            unsigned q = ebuf[lo + i];
            int pos = atomicAdd(&cur[q >> 16], 1);
            colsrc[pos] = (int)(q & 0xffffu);
        }
    }
}

// ---------------- fused attention + aggregation (2 nodes/wave) ------------
// wave = 2 nodes; per node 2 subgroups (16-lane) x unroll 2 = 4 edges/iter.
// lane: nh = lane>>5 (node half), ss = (lane>>4)&1 (edge slot), sl = lane&15
// (channel group, 8 ch via uint4 gather). Butterfly 4 steps within subgroup;
// final combine = shfl_xor(16) once. pk-f32 math.

template<bool OUTBF>
__global__ __launch_bounds__(256) void gat_agg_kernel(
    const unsigned short* __restrict__ xlb, const unsigned short* __restrict__ xrb,
    const float* __restrict__ att, const float* __restrict__ bo,
    const int* __restrict__ offs, const int* __restrict__ col,
    float* __restrict__ outf, unsigned short* __restrict__ outb,
    int n, int apply_act) {
    const int lane = threadIdx.x & 63;
    const int nh   = lane >> 5;              // node half
    const int ss   = (lane >> 4) & 1;        // edge slot within node
    const int sl   = lane & 15;              // channel group
    const int gw   = (blockIdx.x * blockDim.x + threadIdx.x) >> 6;
    const int node = gw * 2 + nh;
    const bool valid = node < n;

    const uint4* xq = (const uint4*)xlb;
    const float4* att4 = (const float4*)att;
    f32x2 xr2[4], at2[4];
    {
        uint4 qa = make_uint4(0u, 0u, 0u, 0u);
        if (valid) qa = ((const uint4*)xrb)[(size_t)node * 16 + sl];
        unpack8p(qa, xr2);
        float4 c = att4[sl * 2], d = att4[sl * 2 + 1];
        at2[0].x = c.x; at2[0].y = c.y; at2[1].x = c.z; at2[1].y = c.w;
        at2[2].x = d.x; at2[2].y = d.y; at2[3].x = d.z; at2[3].y = d.w;
    }

    f32x2 acc[4];
    #pragma unroll
    for (int j = 0; j < 4; ++j) { acc[j].x = 0.f; acc[j].y = 0.f; }
    float den = 0.f;

    int b = 0, cnt = 0;
    if (valid) { b = offs[node]; cnt = offs[node + 1] - b; }

    for (int k = 0; k < cnt; k += 4) {
        const int k0 = k + ss;               // edge index slot 0
        const int k1 = k + 2 + ss;           // edge index slot 1
        const bool e0v = k0 < cnt, e1v = k1 < cnt;
        const int s0 = col[b + (e0v ? k0 : 0)];
        const int s1 = col[b + (e1v ? k1 : 0)];
        uint4 q0 = xq[(size_t)s0 * 16 + sl];
        uint4 q1 = xq[(size_t)s1 * 16 + sl];
        f32x2 v0[4], v1[4];
        unpack8p(q0, v0);
        unpack8p(q1, v1);
        float p0 = logit8p(v0, xr2, at2);
        float p1 = logit8p(v1, xr2, at2);
        p0 += __shfl_xor(p0, 1, 64);  p1 += __shfl_xor(p1, 1, 64);
        p0 += __shfl_xor(p0, 2, 64);  p1 += __shfl_xor(p1, 2, 64);
        p0 += __shfl_xor(p0, 4, 64);  p1 += __shfl_xor(p1, 4, 64);
        p0 += __shfl_xor(p0, 8, 64);  p1 += __shfl_xor(p1, 8, 64);
        const float e0 = e0v ? __expf(p0) : 0.f;
        const float e1 = e1v ? __expf(p1) : 0.f;
        #pragma unroll
        for (int j = 0; j < 4; ++j) {
            acc[j] = v0[j] * e0 + acc[j];
            acc[j] = v1[j] * e1 + acc[j];
        }
        den += e0 + e1;
    }

    // combine the node's two subgroups (lanes ^16)
    den += __shfl_xor(den, 16, 64);
    #pragma unroll
    for (int j = 0; j < 4; ++j) {
        acc[j].x += __shfl_xor(acc[j].x, 16, 64);
        acc[j].y += __shfl_xor(acc[j].y, 16, 64);
    }

    if (valid && ss == 0) {
        const float inv = 1.f / (den + 1e-16f);
        float4 b1 = ((const float4*)bo)[sl * 2];
        float4 b2 = ((const float4*)bo)[sl * 2 + 1];
        float bov[8] = {b1.x, b1.y, b1.z, b1.w, b2.x, b2.y, b2.z, b2.w};
        float o[8];
        #pragma unroll
        for (int j = 0; j < 4; ++j) {
            o[2 * j]     = acc[j].x * inv + bov[2 * j];
            o[2 * j + 1] = acc[j].y * inv + bov[2 * j + 1];
        }
        if (apply_act) {
            #pragma unroll
            for (int j = 0; j < 8; ++j) o[j] = o[j] > 0.f ? o[j] : LRELU_ACT * o[j];
        }
        if (OUTBF) {
            ushort4 u0, u1;
            u0.x = f2bf(o[0]); u0.y = f2bf(o[1]); u0.z = f2bf(o[2]); u0.w = f2bf(o[3]);
            u1.x = f2bf(o[4]); u1.y = f2bf(o[5]); u1.z = f2bf(o[6]); u1.w = f2bf(o[7]);
            ushort4* ob = (ushort4*)(outb + (size_t)node * 128 + sl * 8);
            ob[0] = u0; ob[1] = u1;
        } else {
            float4* o4 = (float4*)(outf + (size_t)node * 128 + sl * 8);
            o4[0] = make_float4(o[0], o[1], o[2], o[3]);
            o4[1] = make_float4(o[4], o[5], o[6], o[7]);
        }
    }
}

// ---------------- host launch ----------------

static inline size_t align_up(size_t x, size_t a) { return (x + a - 1) & ~(a - 1); }

extern "C" void kernel_launch(void* const* d_in, const int* in_sizes, int n_in,
                              void* d_out, int out_size, void* d_ws, size_t ws_size,
                              hipStream_t stream) {
    const float* x   = (const float*)d_in[0];
    const int*   ei  = (const int*)d_in[1];     // int32 per harness contract
    const float* Wl0 = (const float*)d_in[2];
    const float* bl0 = (const float*)d_in[3];
    const float* Wr0 = (const float*)d_in[4];
    const float* br0 = (const float*)d_in[5];
    const float* att0= (const float*)d_in[6];
    const float* bo0 = (const float*)d_in[7];
    const float* Wl1 = (const float*)d_in[8];
    const float* bl1 = (const float*)d_in[9];
    const float* Wr1 = (const float*)d_in[10];
    const float* br1 = (const float*)d_in[11];
    const float* att1= (const float*)d_in[12];
    const float* bo1 = (const float*)d_in[13];
    float* outp = (float*)d_out;

    const int N     = in_sizes[0] / 128;
    const int E     = in_sizes[1] / 2;
    const int Etot  = E + N;
    const int NBUCK = (N + 255) >> 8;        // 196 buckets of 256 nodes
    const int CHUNK = (Etot + SORT_BLOCKS - 1) / SORT_BLOCKS;

    // workspace layout (~40 MB)
    char* p = (char*)d_ws;
    size_t off = 0;
    unsigned short* xlb = (unsigned short*)(p + off);
    off = align_up(off + (size_t)N * 128 * 2, 256);
    unsigned short* xrb = (unsigned short*)(p + off);
    off = align_up(off + (size_t)N * 128 * 2, 256);
    unsigned short* Wb = (unsigned short*)(p + off);
    off = align_up(off + (size_t)4 * 16384 * 2, 256);
    int* histmat= (int*)(p + off); off = align_up(off + (size_t)NBUCK * SORT_BLOCKS * 4, 256);
    int* histpos= (int*)(p + off); off = align_up(off + (size_t)NBUCK * SORT_BLOCKS * 4, 256);
    int* bbase  = (int*)(p + off); off = align_up(off + (size_t)(NBUCK + 1) * 4, 256);
    int* offs   = (int*)(p + off); off = align_up(off + (size_t)(N + 1) * 4, 256);
    int* colsrc = (int*)(p + off); off = align_up(off + (size_t)Etot * 4, 256);
    unsigned* ebuf = (unsigned*)(p + off); off = align_up(off + (size_t)Etot * 4, 256);
    unsigned short* hb = (unsigned short*)d_out;   // inter-layer bf16 h
    (void)ws_size;

    const int nbGemm = (N + 127) / 128;      // 256-thr / 128-row gemm blocks

    // ---- CSR build (counting sort) + fused wconv + fused layer-0 gemm ----
    histA_wconv_kernel<<<SORT_BLOCKS + 256, 256, 0, stream>>>(
        ei, E, Etot, CHUNK, NBUCK, histmat, Wl0, Wr0, Wl1, Wr1, Wb);
    scanB_kernel<<<NBUCK, 256, 0, stream>>>(histmat, NBUCK, histpos, bbase);
    scatter_gemm_kernel<<<SORT_BLOCKS + nbGemm, 256, 0, stream>>>(
        ei, E, Etot, CHUNK, NBUCK, histpos, ebuf,
        x, Wb, bl0, br0, xlb, xrb, N);
    bucket_csr_kernel<<<NBUCK, 512, 0, stream>>>(ebuf, bbase, N, NBUCK, offs, colsrc);

    const int nbAgg = (N + 7) / 8;           // 8 dst nodes per 256-thr block

    // ---- layer 0 agg ----
    gat_agg_kernel<true><<<nbAgg, 256, 0, stream>>>(
        xlb, xrb, att0, bo0, offs, colsrc, nullptr, hb, N, 1);

    // ---- layer 1 ----
    gemm_mfma_kernel<false><<<nbGemm, 256, 0, stream>>>(
        (const void*)hb, Wb + 2 * 16384, bl1, br1, xlb, xrb, N);
    gat_agg_kernel<false><<<nbAgg, 256, 0, stream>>>(
        xlb, xrb, att1, bo1, offs, colsrc, outp, nullptr, N, 0);
}